// Round 1
// baseline (84.100 us; speedup 1.0000x reference)
//
#include <hip/hip_runtime.h>
#include <cstddef>

#define BB 16
#define NN 16385
#define NT 16384
#define CC 64

// ---------------- Phase 1: mask_weight, mask_prob, po/ne accumulators ----------------
__global__ __launch_bounds__(256) void k_phase1(
    const float* __restrict__ x,
    float* __restrict__ mw_ws, float* __restrict__ prob_out,
    float* __restrict__ acc_po, float* __restrict__ acc_ne,
    float* __restrict__ cnt)
{
  const int b = blockIdx.y;
  const int tid = threadIdx.x;
  const int lane = tid & 63, wave = tid >> 6;
  const int g = lane & 15, t = lane >> 4;
  const int c0 = g * 4;
  const float* xb = x + (size_t)b * NN * CC;

  const float4 wt4 = *reinterpret_cast<const float4*>(xb + c0);

  float apo[4] = {0.f, 0.f, 0.f, 0.f};
  float ane[4] = {0.f, 0.f, 0.f, 0.f};
  float cntl = 0.f;

  const int ngroups = NT / 4;  // 4096 groups of 4 tokens
  for (int grp = blockIdx.x * 4 + wave; grp < ngroups; grp += gridDim.x * 4) {
    const int n0 = grp * 4;           // token index base within [0,NT)
    const int row = 1 + n0 + t;       // row in x
    float4 xv = *reinterpret_cast<const float4*>(xb + (size_t)row * CC + c0);
    float p = xv.x * wt4.x + xv.y * wt4.y + xv.z * wt4.z + xv.w * wt4.w;
    p += __shfl_xor(p, 1);
    p += __shfl_xor(p, 2);
    p += __shfl_xor(p, 4);
    p += __shfl_xor(p, 8);
    // p = mask_weight for token n0+t (all 16 lanes of group have it)
    const bool m = p > 0.f;
    const float po = m ? p : 0.f;
    const float ne = m ? 0.f : p;
    apo[0] += po * xv.x; apo[1] += po * xv.y; apo[2] += po * xv.z; apo[3] += po * xv.w;
    ane[0] += ne * xv.x; ane[1] += ne * xv.y; ane[2] += ne * xv.z; ane[3] += ne * xv.w;
    if (g == 0) {
      const int nt = n0 + t;
      mw_ws[b * NT + nt] = p;
      prob_out[(size_t)b * NT + nt] = 1.f / (1.f + __expf(-p));
      if (m) cntl += 1.f;
    }
  }

  // reduce column partials across the 4 token-groups in the wave
  #pragma unroll
  for (int i = 0; i < 4; ++i) {
    apo[i] += __shfl_xor(apo[i], 16); apo[i] += __shfl_xor(apo[i], 32);
    ane[i] += __shfl_xor(ane[i], 16); ane[i] += __shfl_xor(ane[i], 32);
  }
  cntl += __shfl_xor(cntl, 16);
  cntl += __shfl_xor(cntl, 32);

  __shared__ float s_po[4][64];
  __shared__ float s_ne[4][64];
  __shared__ float s_cnt[4];
  if (t == 0) {  // lanes 0..15 hold complete wave sums for cols c0..c0+3
    #pragma unroll
    for (int i = 0; i < 4; ++i) { s_po[wave][c0 + i] = apo[i]; s_ne[wave][c0 + i] = ane[i]; }
  }
  if (lane == 0) s_cnt[wave] = cntl;
  __syncthreads();
  if (wave == 0) {
    const float sp = s_po[0][lane] + s_po[1][lane] + s_po[2][lane] + s_po[3][lane];
    const float sn = s_ne[0][lane] + s_ne[1][lane] + s_ne[2][lane] + s_ne[3][lane];
    atomicAdd(acc_po + b * CC + lane, sp);
    atomicAdd(acc_ne + b * CC + lane, sn);
    if (lane == 0) atomicAdd(cnt + b, s_cnt[0] + s_cnt[1] + s_cnt[2] + s_cnt[3]);
  }
}

// ---------------- Phase 2: LN + fold weights into A (64x3) and v' (3x64) ----------------
__global__ __launch_bounds__(64) void k_phase2(
    const float* __restrict__ x, const float* __restrict__ Wq,
    const float* __restrict__ Wkv, const float* __restrict__ ln_g,
    const float* __restrict__ ln_b, const float* __restrict__ Wp,
    const float* __restrict__ acc_po, const float* __restrict__ acc_ne,
    const float* __restrict__ cnt,
    float* __restrict__ A_ws, float* __restrict__ vp_ws, float* __restrict__ flag_ws)
{
  const int b = blockIdx.x, j = threadIdx.x;
  const float count = cnt[b];
  const bool flag = (count == 0.f);

  float rows[3];
  rows[0] = x[(size_t)b * NN * CC + j];                 // wt
  const float po = acc_po[b * CC + j], ne = acc_ne[b * CC + j];
  rows[1] = flag ? ne : po;   // count==0: mask->ones, po becomes sum(mw*t) == ne_acc
  rows[2] = flag ? 0.f : ne;

  __shared__ float y[3][64];
  __shared__ float kk[3][64];
  __shared__ float vv[3][64];

  #pragma unroll
  for (int r = 0; r < 3; ++r) {
    const float v = rows[r];
    float s = v;
    for (int o = 1; o < 64; o <<= 1) s += __shfl_xor(s, o);
    const float mu = s * (1.f / 64.f);
    const float d = v - mu;
    float s2 = d * d;
    for (int o = 1; o < 64; o <<= 1) s2 += __shfl_xor(s2, o);
    const float var = s2 * (1.f / 64.f);
    y[r][j] = d * rsqrtf(var + 1e-5f) * ln_g[j] + ln_b[j];
  }
  __syncthreads();

  #pragma unroll
  for (int r = 0; r < 3; ++r) {
    float sk = 0.f, sv = 0.f;
    for (int c = 0; c < 64; ++c) {
      const float yv = y[r][c];
      sk += yv * Wkv[c * 128 + j];
      sv += yv * Wkv[c * 128 + 64 + j];
    }
    kk[r][j] = sk; vv[r][j] = sv;
  }
  __syncthreads();

  const float scale = 0.125f;  // 64^-0.5
  #pragma unroll
  for (int m = 0; m < 3; ++m) {
    float sa = 0.f;
    for (int d = 0; d < 64; ++d) sa += Wq[j * 64 + d] * kk[m][d];
    A_ws[b * 192 + m * 64 + j] = sa * scale;
    float sp = 0.f;
    for (int c = 0; c < 64; ++c) sp += vv[m][c] * Wp[c * 64 + j];
    vp_ws[b * 192 + m * 64 + j] = sp;
  }
  if (j == 0) flag_ws[b] = flag ? 1.f : 0.f;
}

// ---------------- Phase 3: logits(3) -> softmax -> out, plus mask write ----------------
__global__ __launch_bounds__(256) void k_phase3(
    const float* __restrict__ x, const float* __restrict__ A_ws,
    const float* __restrict__ vp_ws, const float* __restrict__ bp,
    const float* __restrict__ flag_ws, const float* __restrict__ mw_ws,
    float* __restrict__ out, float* __restrict__ mask_out)
{
  const int b = blockIdx.y;
  const int tid = threadIdx.x, lane = tid & 63, wave = tid >> 6;
  const int g = lane & 15, t = lane >> 4, c0 = g * 4;

  const float4 A0 = *reinterpret_cast<const float4*>(A_ws + b * 192 + 0 * 64 + c0);
  const float4 A1 = *reinterpret_cast<const float4*>(A_ws + b * 192 + 1 * 64 + c0);
  const float4 A2 = *reinterpret_cast<const float4*>(A_ws + b * 192 + 2 * 64 + c0);
  const float4 V0 = *reinterpret_cast<const float4*>(vp_ws + b * 192 + 0 * 64 + c0);
  const float4 V1 = *reinterpret_cast<const float4*>(vp_ws + b * 192 + 1 * 64 + c0);
  const float4 V2 = *reinterpret_cast<const float4*>(vp_ws + b * 192 + 2 * 64 + c0);
  const float4 BP = *reinterpret_cast<const float4*>(bp + c0);
  const float flag = flag_ws[b];

  const float* xb = x + (size_t)b * NN * CC;
  float* ob = out + (size_t)b * NN * CC;

  const int ngroups = (NN + 3) / 4;  // 4097 (last group has 1 valid token)
  for (int grp = blockIdx.x * 4 + wave; grp < ngroups; grp += gridDim.x * 4) {
    const int n = grp * 4 + t;
    const bool valid = n < NN;
    float4 xv;
    if (valid) xv = *reinterpret_cast<const float4*>(xb + (size_t)n * CC + c0);
    else { xv.x = xv.y = xv.z = xv.w = 0.f; }

    float p0 = xv.x * A0.x + xv.y * A0.y + xv.z * A0.z + xv.w * A0.w;
    float p1 = xv.x * A1.x + xv.y * A1.y + xv.z * A1.z + xv.w * A1.w;
    float p2 = xv.x * A2.x + xv.y * A2.y + xv.z * A2.z + xv.w * A2.w;
    #pragma unroll
    for (int o = 1; o < 16; o <<= 1) {
      p0 += __shfl_xor(p0, o);
      p1 += __shfl_xor(p1, o);
      p2 += __shfl_xor(p2, o);
    }
    const float mx = fmaxf(p0, fmaxf(p1, p2));
    float e0 = __expf(p0 - mx), e1 = __expf(p1 - mx), e2 = __expf(p2 - mx);
    const float inv = 1.f / (e0 + e1 + e2);
    e0 *= inv; e1 *= inv; e2 *= inv;

    float4 o4;
    o4.x = BP.x + e0 * V0.x + e1 * V1.x + e2 * V2.x;
    o4.y = BP.y + e0 * V0.y + e1 * V1.y + e2 * V2.y;
    o4.z = BP.z + e0 * V0.z + e1 * V1.z + e2 * V2.z;
    o4.w = BP.w + e0 * V0.w + e1 * V1.w + e2 * V2.w;
    if (valid) *reinterpret_cast<float4*>(ob + (size_t)n * CC + c0) = o4;

    if (g == 0 && valid && n >= 1) {
      const float mwv = mw_ws[b * NT + n - 1];
      mask_out[b * NT + n - 1] = (flag != 0.f) ? 1.f : (mwv > 0.f ? 1.f : 0.f);
    }
  }
}

extern "C" void kernel_launch(void* const* d_in, const int* in_sizes, int n_in,
                              void* d_out, int out_size, void* d_ws, size_t ws_size,
                              hipStream_t stream) {
  (void)in_sizes; (void)n_in; (void)out_size; (void)ws_size;
  const float* x    = (const float*)d_in[0];
  const float* Wq   = (const float*)d_in[1];
  const float* Wkv  = (const float*)d_in[2];
  const float* ln_g = (const float*)d_in[3];
  const float* ln_b = (const float*)d_in[4];
  const float* Wp   = (const float*)d_in[5];
  const float* bp   = (const float*)d_in[6];

  float* out      = (float*)d_out;                       // B*N*C
  float* mask_out = out + (size_t)BB * NN * CC;          // B*NT
  float* prob_out = mask_out + (size_t)BB * NT;          // B*NT

  float* ws      = (float*)d_ws;
  float* mw_ws   = ws;                                   // B*NT
  float* acc_po  = ws + (size_t)BB * NT;                 // B*64
  float* acc_ne  = acc_po + BB * CC;                     // B*64
  float* cnt     = acc_ne + BB * CC;                     // B
  float* A_ws    = cnt + BB;                             // B*192
  float* vp_ws   = A_ws + BB * 192;                      // B*192
  float* flag_ws = vp_ws + BB * 192;                     // B

  // zero the accumulators (acc_po, acc_ne, cnt are contiguous)
  hipMemsetAsync(acc_po, 0, (size_t)(BB * CC * 2 + BB) * sizeof(float), stream);

  k_phase1<<<dim3(64, BB), 256, 0, stream>>>(x, mw_ws, prob_out, acc_po, acc_ne, cnt);
  k_phase2<<<BB, 64, 0, stream>>>(x, Wq, Wkv, ln_g, ln_b, Wp, acc_po, acc_ne, cnt,
                                  A_ws, vp_ws, flag_ws);
  k_phase3<<<dim3(128, BB), 256, 0, stream>>>(x, A_ws, vp_ws, bp, flag_ws, mw_ws,
                                              out, mask_out);
}